// Round 1
// baseline (146.180 us; speedup 1.0000x reference)
//
#include <hip/hip_runtime.h>

// ---------------------------------------------------------------------------
// Fast math helpers (hardware transcendental pipe). Accuracy ~1e-6 rel, far
// inside the 2.5e-2 absmax threshold; recurrence is contractive (f<1).
// ---------------------------------------------------------------------------
__device__ __forceinline__ float fast_exp(float x) {
  return __builtin_amdgcn_exp2f(x * 1.4426950408889634f);
}
__device__ __forceinline__ float fast_rcp(float x) {
  return __builtin_amdgcn_rcpf(x);
}
__device__ __forceinline__ float fast_cos(float x) {
  // v_cos takes revolutions; v_fract does the range reduction.
  return __builtin_amdgcn_cosf(__builtin_amdgcn_fractf(x * 0.15915494309189535f));
}
__device__ __forceinline__ float fast_sigmoid(float x) {
  return fast_rcp(1.0f + fast_exp(-x));
}
__device__ __forceinline__ float fast_tanh(float x) {
  return 1.0f - 2.0f * fast_rcp(1.0f + fast_exp(2.0f * x));
}

// ---------------------------------------------------------------------------
// Kernel 1: precompute x-part of gate activations.
//   Z[t][k][b][g] = x[t,b,:] . W_g[row_k, :D] + fold
// where k in {0,1,2} maps to linear-output rows {0,1,3} (row 2 is provably
// dead: RZ on |0> is a global phase). fold = bias + theta for rows 0,3.
// ---------------------------------------------------------------------------
__global__ __launch_bounds__(256) void qlstm_gemm(
    const float* __restrict__ x,
    const float* __restrict__ Wf, const float* __restrict__ bf,
    const float* __restrict__ Wi, const float* __restrict__ bi,
    const float* __restrict__ Wu, const float* __restrict__ bu,
    const float* __restrict__ Wo, const float* __restrict__ bo,
    const float* __restrict__ thf, const float* __restrict__ thi,
    const float* __restrict__ thu, const float* __restrict__ tho,
    float* __restrict__ Z, long long rows, int B, int D)
{
  long long r = (long long)blockIdx.x * 256 + threadIdx.x;
  if (r >= rows) return;
  const float* Ws[4] = {Wf, Wi, Wu, Wo};
  const float* bs[4] = {bf, bi, bu, bo};
  const float* ts[4] = {thf, thi, thu, tho};
  const int ldw = D + 4;

  float acc[12];
#pragma unroll
  for (int g = 0; g < 4; ++g) {
    acc[g * 3 + 0] = bs[g][0] + ts[g][0];  // theta0 folded
    acc[g * 3 + 1] = bs[g][1];
    acc[g * 3 + 2] = bs[g][3] + ts[g][3];  // theta3 folded
  }

  const float* xp = x + r * (long long)D;
#pragma unroll 8
  for (int k = 0; k < D; k += 4) {
    float4 xv = *(const float4*)(xp + k);
#pragma unroll
    for (int g = 0; g < 4; ++g) {
      const float* W = Ws[g];
#pragma unroll
      for (int jj = 0; jj < 3; ++jj) {
        int row = (jj == 2) ? 3 : jj;
        const float* wp = W + row * ldw + k;  // wave-uniform -> s_loads
        acc[g * 3 + jj] += xv.x * wp[0] + xv.y * wp[1] + xv.z * wp[2] + xv.w * wp[3];
      }
    }
  }

  long long t = r / B;
  int b = (int)(r - t * B);
  float4 s0 = make_float4(acc[0], acc[3], acc[6], acc[9]);   // a0 per gate
  float4 s1 = make_float4(acc[1], acc[4], acc[7], acc[10]);  // a1 per gate
  float4 s2 = make_float4(acc[2], acc[5], acc[8], acc[11]);  // a3 per gate
  *(float4*)(Z + ((t * 3 + 0) * (long long)B + b) * 4) = s0;
  *(float4*)(Z + ((t * 3 + 1) * (long long)B + b) * 4) = s1;
  *(float4*)(Z + ((t * 3 + 2) * (long long)B + b) * 4) = s2;
}

// ---------------------------------------------------------------------------
// Shared per-thread constants + one LSTM step from precomputed a[12]
// (a[g*3+{0,1,2}] = wire0/wire1/wire3 angles, h-contribution included).
// ---------------------------------------------------------------------------
struct GK {
  float wh[4][3][4];  // [gate][comp(0,1,3)][h index]
  float ct1[4];       // cos(theta1)
  float m2c[4];       // cos(theta2)
};

__device__ __forceinline__ void load_gk(GK& K,
    const float* Wf, const float* Wi, const float* Wu, const float* Wo,
    const float* thf, const float* thi, const float* thu, const float* tho,
    int D)
{
  const float* Ws[4] = {Wf, Wi, Wu, Wo};
  const float* ts[4] = {thf, thi, thu, tho};
  const int ldw = D + 4;
#pragma unroll
  for (int g = 0; g < 4; ++g) {
#pragma unroll
    for (int jj = 0; jj < 3; ++jj) {
      int row = (jj == 2) ? 3 : jj;
#pragma unroll
      for (int q = 0; q < 4; ++q)
        K.wh[g][jj][q] = Ws[g][row * ldw + D + q];
    }
    K.ct1[g] = fast_cos(ts[g][1]);
    K.m2c[g] = fast_cos(ts[g][2]);
  }
}

__device__ __forceinline__ void qlstm_step(const float a[12], const GK& K,
                                           float h[4], float c[4])
{
  float gv[4][4];
#pragma unroll
  for (int g = 0; g < 4; ++g) {
    float m0 = fast_cos(a[g * 3 + 0]);
    float m1 = K.ct1[g] * fast_cos(a[g * 3 + 1]);
    float m3 = fast_cos(a[g * 3 + 2]);
    float m01 = m0 * m1;
    float m23 = K.m2c[g] * m3;
    gv[g][0] = m1 * m23;          // <Z0> = m1 m2 m3
    gv[g][1] = m01;               // <Z1> = m0 m1
    gv[g][2] = m01 * K.m2c[g];    // <Z2> = m0 m1 m2
    gv[g][3] = m01 * m23;         // <Z3> = m0 m1 m2 m3
  }
#pragma unroll
  for (int q = 0; q < 4; ++q) {
    float fg = fast_sigmoid(gv[0][q]);
    float ig = fast_sigmoid(gv[1][q]);
    float ug = fast_tanh(gv[2][q]);
    float og = fast_sigmoid(gv[3][q]);
    c[q] = fg * c[q] + ig * ug;
    h[q] = og * fast_tanh(c[q]);
  }
}

// ---------------------------------------------------------------------------
// Kernel 2: sequential scan, one thread per batch element.
// ---------------------------------------------------------------------------
__global__ __launch_bounds__(256) void qlstm_scan(
    const float* __restrict__ Z,
    const float* __restrict__ Wf, const float* __restrict__ Wi,
    const float* __restrict__ Wu, const float* __restrict__ Wo,
    const float* __restrict__ thf, const float* __restrict__ thi,
    const float* __restrict__ thu, const float* __restrict__ tho,
    float* __restrict__ out, int T, int B, int D)
{
  int b = blockIdx.x * 256 + threadIdx.x;
  if (b >= B) return;
  GK K;
  load_gk(K, Wf, Wi, Wu, Wo, thf, thi, thu, tho, D);

  float h[4] = {0.f, 0.f, 0.f, 0.f};
  float c[4] = {0.f, 0.f, 0.f, 0.f};
  float* hx  = out + (size_t)T * B * 4;
  float* cxp = hx + (size_t)B * 4;

  float4 zb0 = *(const float4*)(Z + ((size_t)0 * B + b) * 4);
  float4 zb1 = *(const float4*)(Z + ((size_t)1 * B + b) * 4);
  float4 zb2 = *(const float4*)(Z + ((size_t)2 * B + b) * 4);

  for (int t = 0; t < T; ++t) {
    float a[12] = {zb0.x, zb1.x, zb2.x,  zb0.y, zb1.y, zb2.y,
                   zb0.z, zb1.z, zb2.z,  zb0.w, zb1.w, zb2.w};
    if (t + 1 < T) {  // prefetch next step's activations (no recurrence dep)
      zb0 = *(const float4*)(Z + (((size_t)(t + 1) * 3 + 0) * B + b) * 4);
      zb1 = *(const float4*)(Z + (((size_t)(t + 1) * 3 + 1) * B + b) * 4);
      zb2 = *(const float4*)(Z + (((size_t)(t + 1) * 3 + 2) * B + b) * 4);
    }
#pragma unroll
    for (int g = 0; g < 4; ++g) {
#pragma unroll
      for (int jj = 0; jj < 3; ++jj) {
        a[g * 3 + jj] += K.wh[g][jj][0] * h[0] + K.wh[g][jj][1] * h[1]
                       + K.wh[g][jj][2] * h[2] + K.wh[g][jj][3] * h[3];
      }
    }
    qlstm_step(a, K, h, c);
    *(float4*)(out + ((size_t)t * B + b) * 4) = make_float4(h[0], h[1], h[2], h[3]);
  }
  *(float4*)(hx + (size_t)b * 4)  = make_float4(h[0], h[1], h[2], h[3]);
  *(float4*)(cxp + (size_t)b * 4) = make_float4(c[0], c[1], c[2], c[3]);
}

// ---------------------------------------------------------------------------
// Fallback (only if workspace can't hold Z): fused, slow but correct.
// ---------------------------------------------------------------------------
__global__ __launch_bounds__(256) void qlstm_fused(
    const float* __restrict__ x,
    const float* __restrict__ Wf, const float* __restrict__ bf,
    const float* __restrict__ Wi, const float* __restrict__ bi,
    const float* __restrict__ Wu, const float* __restrict__ bu,
    const float* __restrict__ Wo, const float* __restrict__ bo,
    const float* __restrict__ thf, const float* __restrict__ thi,
    const float* __restrict__ thu, const float* __restrict__ tho,
    float* __restrict__ out, int T, int B, int D)
{
  int b = blockIdx.x * 256 + threadIdx.x;
  if (b >= B) return;
  GK K;
  load_gk(K, Wf, Wi, Wu, Wo, thf, thi, thu, tho, D);
  const float* Ws[4] = {Wf, Wi, Wu, Wo};
  const float* bs[4] = {bf, bi, bu, bo};
  const float* ts[4] = {thf, thi, thu, tho};
  const int ldw = D + 4;

  float base[12];
#pragma unroll
  for (int g = 0; g < 4; ++g) {
    base[g * 3 + 0] = bs[g][0] + ts[g][0];
    base[g * 3 + 1] = bs[g][1];
    base[g * 3 + 2] = bs[g][3] + ts[g][3];
  }

  float h[4] = {0.f, 0.f, 0.f, 0.f};
  float c[4] = {0.f, 0.f, 0.f, 0.f};
  float* hx  = out + (size_t)T * B * 4;
  float* cxp = hx + (size_t)B * 4;

  for (int t = 0; t < T; ++t) {
    float a[12];
#pragma unroll
    for (int j = 0; j < 12; ++j) a[j] = base[j];
    const float* xp = x + ((size_t)t * B + b) * D;
    for (int k = 0; k < D; k += 4) {
      float4 xv = *(const float4*)(xp + k);
#pragma unroll
      for (int g = 0; g < 4; ++g) {
        const float* W = Ws[g];
#pragma unroll
        for (int jj = 0; jj < 3; ++jj) {
          int row = (jj == 2) ? 3 : jj;
          const float* wp = W + row * ldw + k;
          a[g * 3 + jj] += xv.x * wp[0] + xv.y * wp[1] + xv.z * wp[2] + xv.w * wp[3];
        }
      }
    }
#pragma unroll
    for (int g = 0; g < 4; ++g) {
#pragma unroll
      for (int jj = 0; jj < 3; ++jj) {
        a[g * 3 + jj] += K.wh[g][jj][0] * h[0] + K.wh[g][jj][1] * h[1]
                       + K.wh[g][jj][2] * h[2] + K.wh[g][jj][3] * h[3];
      }
    }
    qlstm_step(a, K, h, c);
    *(float4*)(out + ((size_t)t * B + b) * 4) = make_float4(h[0], h[1], h[2], h[3]);
  }
  *(float4*)(hx + (size_t)b * 4)  = make_float4(h[0], h[1], h[2], h[3]);
  *(float4*)(cxp + (size_t)b * 4) = make_float4(c[0], c[1], c[2], c[3]);
}

// ---------------------------------------------------------------------------
extern "C" void kernel_launch(void* const* d_in, const int* in_sizes, int n_in,
                              void* d_out, int out_size, void* d_ws, size_t ws_size,
                              hipStream_t stream)
{
  const float* x   = (const float*)d_in[0];
  const float* Wf  = (const float*)d_in[1];
  const float* bf  = (const float*)d_in[2];
  const float* Wi  = (const float*)d_in[3];
  const float* bi  = (const float*)d_in[4];
  const float* Wu  = (const float*)d_in[5];
  const float* bu  = (const float*)d_in[6];
  const float* Wo  = (const float*)d_in[7];
  const float* bo  = (const float*)d_in[8];
  const float* thf = (const float*)d_in[9];
  const float* thi = (const float*)d_in[10];
  const float* thu = (const float*)d_in[11];
  const float* tho = (const float*)d_in[12];

  int DH = in_sizes[1] / 4;                 // D + H (H = 4)
  int D  = DH - 4;                          // 128
  long long TB = (long long)in_sizes[0] / D;        // T*B
  int B = (int)(((long long)out_size - 4 * TB) / 8);  // out = 4*T*B + 8*B
  int T = (int)(TB / B);

  size_t zbytes = (size_t)TB * 12 * sizeof(float);
  if (ws_size >= zbytes) {
    float* Z = (float*)d_ws;
    int gblocks = (int)((TB + 255) / 256);
    qlstm_gemm<<<gblocks, 256, 0, stream>>>(x, Wf, bf, Wi, bi, Wu, bu, Wo, bo,
                                            thf, thi, thu, tho, Z, TB, B, D);
    qlstm_scan<<<(B + 255) / 256, 256, 0, stream>>>(Z, Wf, Wi, Wu, Wo,
                                                    thf, thi, thu, tho,
                                                    (float*)d_out, T, B, D);
  } else {
    qlstm_fused<<<(B + 255) / 256, 256, 0, stream>>>(x, Wf, bf, Wi, bi, Wu, bu, Wo, bo,
                                                     thf, thi, thu, tho,
                                                     (float*)d_out, T, B, D);
  }
}

// Round 2
// 115.519 us; speedup vs baseline: 1.2654x; 1.2654x over previous
//
#include <hip/hip_runtime.h>

// ---------------------------------------------------------------------------
// Fast math helpers (hardware transcendental pipe). Accuracy ~1e-6 rel, far
// inside the 2.5e-2 absmax threshold; recurrence is contractive (f<1).
// ---------------------------------------------------------------------------
__device__ __forceinline__ float fast_exp(float x) {
  return __builtin_amdgcn_exp2f(x * 1.4426950408889634f);
}
__device__ __forceinline__ float fast_rcp(float x) {
  return __builtin_amdgcn_rcpf(x);
}
__device__ __forceinline__ float fast_cos(float x) {
  // v_cos takes revolutions; v_fract does the range reduction.
  return __builtin_amdgcn_cosf(__builtin_amdgcn_fractf(x * 0.15915494309189535f));
}
__device__ __forceinline__ float fast_sigmoid(float x) {
  return fast_rcp(1.0f + fast_exp(-x));
}
__device__ __forceinline__ float fast_tanh(float x) {
  return 1.0f - 2.0f * fast_rcp(1.0f + fast_exp(2.0f * x));
}

// ---------------------------------------------------------------------------
// Kernel 1: precompute x-part of gate activations, LDS-staged for coalescing.
//   Z[t][j][b][g] = x[t,b,:] . W_g[row_j, :D] + fold   (j in {0,1,2} -> linear
// rows {0,1,3}; row 2 is dead: RZ on |0> is a global phase). fold = bias+theta
// for rows 0,3.
// Block: 256 threads = 256 output rows; K chunked in 32-col tiles via LDS.
// ---------------------------------------------------------------------------
__global__ __launch_bounds__(256) void qlstm_gemm(
    const float* __restrict__ x,
    const float* __restrict__ Wf, const float* __restrict__ bf,
    const float* __restrict__ Wi, const float* __restrict__ bi,
    const float* __restrict__ Wu, const float* __restrict__ bu,
    const float* __restrict__ Wo, const float* __restrict__ bo,
    const float* __restrict__ thf, const float* __restrict__ thi,
    const float* __restrict__ thu, const float* __restrict__ tho,
    float* __restrict__ Z, long long rows, int B, int D)
{
  __shared__ float tile[256][36];  // LD=36: 2-way bank aliasing only (free)
  const long long base = (long long)blockIdx.x * 256;
  const int tid = threadIdx.x;
  const long long r = base + tid;
  const bool valid = r < rows;
  const int ldw = D + 4;
  const float* Ws[4] = {Wf, Wi, Wu, Wo};
  const float* bs[4] = {bf, bi, bu, bo};
  const float* ts[4] = {thf, thi, thu, tho};

  float acc[12];
#pragma unroll
  for (int g = 0; g < 4; ++g) {
    acc[g * 3 + 0] = bs[g][0] + ts[g][0];  // theta0 folded
    acc[g * 3 + 1] = bs[g][1];
    acc[g * 3 + 2] = bs[g][3] + ts[g][3];  // theta3 folded
  }

  const int nkc = D >> 5;  // D assumed multiple of 32 (D=128)
  for (int kc = 0; kc < nkc; ++kc) {
    // stage 256 rows x 32 cols, coalesced
#pragma unroll
    for (int i = 0; i < 8; ++i) {
      int flat = i * 1024 + tid * 4;
      int row = flat >> 5, col = flat & 31;
      long long gr = base + row;
      if (gr < rows) {
        float4 v = *(const float4*)(x + gr * (long long)D + kc * 32 + col);
        *(float4*)&tile[row][col] = v;
      }
    }
    __syncthreads();
    if (valid) {
#pragma unroll
      for (int k = 0; k < 32; k += 4) {
        float4 xv = *(float4*)&tile[tid][k];
#pragma unroll
        for (int g = 0; g < 4; ++g) {
#pragma unroll
          for (int jj = 0; jj < 3; ++jj) {
            int row2 = (jj == 2) ? 3 : jj;
            const float* wp = Ws[g] + row2 * ldw + kc * 32 + k;  // uniform -> s_load
            acc[g * 3 + jj] += xv.x * wp[0] + xv.y * wp[1] + xv.z * wp[2] + xv.w * wp[3];
          }
        }
      }
    }
    __syncthreads();
  }

  if (valid) {
    long long t = r / B;
    int b = (int)(r - t * B);
    float4 s0 = make_float4(acc[0], acc[3], acc[6], acc[9]);   // a0 per gate
    float4 s1 = make_float4(acc[1], acc[4], acc[7], acc[10]);  // a1 per gate
    float4 s2 = make_float4(acc[2], acc[5], acc[8], acc[11]);  // a3 per gate
    *(float4*)(Z + ((t * 3 + 0) * (long long)B + b) * 4) = s0;
    *(float4*)(Z + ((t * 3 + 1) * (long long)B + b) * 4) = s1;
    *(float4*)(Z + ((t * 3 + 2) * (long long)B + b) * 4) = s2;
  }
}

// ---------------------------------------------------------------------------
// Per-thread constants + one LSTM step from precomputed a[12]
// (a[g*3+{0,1,2}] = wire0/wire1/wire3 angles, h-contribution included).
// ---------------------------------------------------------------------------
struct GK {
  float wh[4][3][4];  // [gate][comp(0,1,3)][h index]
  float ct1[4];       // cos(theta1)
  float m2c[4];       // cos(theta2)
};

__device__ __forceinline__ void load_gk(GK& K,
    const float* Wf, const float* Wi, const float* Wu, const float* Wo,
    const float* thf, const float* thi, const float* thu, const float* tho,
    int D)
{
  const float* Ws[4] = {Wf, Wi, Wu, Wo};
  const float* ts[4] = {thf, thi, thu, tho};
  const int ldw = D + 4;
#pragma unroll
  for (int g = 0; g < 4; ++g) {
#pragma unroll
    for (int jj = 0; jj < 3; ++jj) {
      int row = (jj == 2) ? 3 : jj;
#pragma unroll
      for (int q = 0; q < 4; ++q)
        K.wh[g][jj][q] = Ws[g][row * ldw + D + q];
    }
    K.ct1[g] = fast_cos(ts[g][1]);
    K.m2c[g] = fast_cos(ts[g][2]);
  }
}

__device__ __forceinline__ void qlstm_step(const float a[12], const GK& K,
                                           float h[4], float c[4])
{
  float gv[4][4];
#pragma unroll
  for (int g = 0; g < 4; ++g) {
    float m0 = fast_cos(a[g * 3 + 0]);
    float m1 = K.ct1[g] * fast_cos(a[g * 3 + 1]);
    float m3 = fast_cos(a[g * 3 + 2]);
    float m01 = m0 * m1;
    float m23 = K.m2c[g] * m3;
    gv[g][0] = m1 * m23;          // <Z0> = m1 m2 m3
    gv[g][1] = m01;               // <Z1> = m0 m1
    gv[g][2] = m01 * K.m2c[g];    // <Z2> = m0 m1 m2
    gv[g][3] = m01 * m23;         // <Z3> = m0 m1 m2 m3
  }
#pragma unroll
  for (int q = 0; q < 4; ++q) {
    float fg = fast_sigmoid(gv[0][q]);
    float ig = fast_sigmoid(gv[1][q]);
    float ug = fast_tanh(gv[2][q]);
    float og = fast_sigmoid(gv[3][q]);
    c[q] = fg * c[q] + ig * ug;
    h[q] = og * fast_tanh(c[q]);
  }
}

__device__ __forceinline__ void scan_step(const float4& z0, const float4& z1,
                                          const float4& z2, const GK& K,
                                          float h[4], float c[4])
{
  float a[12] = {z0.x, z1.x, z2.x,  z0.y, z1.y, z2.y,
                 z0.z, z1.z, z2.z,  z0.w, z1.w, z2.w};
#pragma unroll
  for (int g = 0; g < 4; ++g) {
#pragma unroll
    for (int jj = 0; jj < 3; ++jj) {
      a[g * 3 + jj] += K.wh[g][jj][0] * h[0] + K.wh[g][jj][1] * h[1]
                     + K.wh[g][jj][2] * h[2] + K.wh[g][jj][3] * h[3];
    }
  }
  qlstm_step(a, K, h, c);
}

// ---------------------------------------------------------------------------
// Kernel 2: sequential scan, one thread per batch element, depth-4 prefetch.
// ---------------------------------------------------------------------------
__global__ __launch_bounds__(64) void qlstm_scan(
    const float* __restrict__ Z,
    const float* __restrict__ Wf, const float* __restrict__ Wi,
    const float* __restrict__ Wu, const float* __restrict__ Wo,
    const float* __restrict__ thf, const float* __restrict__ thi,
    const float* __restrict__ thu, const float* __restrict__ tho,
    float* __restrict__ out, int T, int B, int D)
{
  int b = blockIdx.x * 64 + threadIdx.x;
  if (b >= B) return;
  GK K;
  load_gk(K, Wf, Wi, Wu, Wo, thf, thi, thu, tho, D);

  float h[4] = {0.f, 0.f, 0.f, 0.f};
  float c[4] = {0.f, 0.f, 0.f, 0.f};
  float* hx  = out + (size_t)T * B * 4;
  float* cxp = hx + (size_t)B * 4;

  const float4* Zv = (const float4*)Z;  // index: (t*3 + j)*B + b
  auto ldz = [&](int t, float4& z0, float4& z1, float4& z2) {
    size_t zb = (size_t)t * 3 * B + b;
    z0 = Zv[zb];
    z1 = Zv[zb + (size_t)B];
    z2 = Zv[zb + 2 * (size_t)B];
  };

  // depth-4 prefetch pipeline (named buffers: rule #20, no runtime indexing)
  float4 A0, A1, A2, Bb0, Bb1, Bb2, C0, C1, C2, D0, D1, D2;
  if (T > 0) ldz(0, A0, A1, A2);
  if (T > 1) ldz(1, Bb0, Bb1, Bb2);
  if (T > 2) ldz(2, C0, C1, C2);
  if (T > 3) ldz(3, D0, D1, D2);

  int T4 = T & ~3;
  for (int t = 0; t < T4; t += 4) {
    {
      float4 z0 = A0, z1 = A1, z2 = A2;
      if (t + 4 < T) ldz(t + 4, A0, A1, A2);
      scan_step(z0, z1, z2, K, h, c);
      *(float4*)(out + ((size_t)t * B + b) * 4) = make_float4(h[0], h[1], h[2], h[3]);
    }
    {
      float4 z0 = Bb0, z1 = Bb1, z2 = Bb2;
      if (t + 5 < T) ldz(t + 5, Bb0, Bb1, Bb2);
      scan_step(z0, z1, z2, K, h, c);
      *(float4*)(out + ((size_t)(t + 1) * B + b) * 4) = make_float4(h[0], h[1], h[2], h[3]);
    }
    {
      float4 z0 = C0, z1 = C1, z2 = C2;
      if (t + 6 < T) ldz(t + 6, C0, C1, C2);
      scan_step(z0, z1, z2, K, h, c);
      *(float4*)(out + ((size_t)(t + 2) * B + b) * 4) = make_float4(h[0], h[1], h[2], h[3]);
    }
    {
      float4 z0 = D0, z1 = D1, z2 = D2;
      if (t + 7 < T) ldz(t + 7, D0, D1, D2);
      scan_step(z0, z1, z2, K, h, c);
      *(float4*)(out + ((size_t)(t + 3) * B + b) * 4) = make_float4(h[0], h[1], h[2], h[3]);
    }
  }
  for (int t = T4; t < T; ++t) {  // tail (unused for T%4==0)
    float4 z0, z1, z2;
    ldz(t, z0, z1, z2);
    scan_step(z0, z1, z2, K, h, c);
    *(float4*)(out + ((size_t)t * B + b) * 4) = make_float4(h[0], h[1], h[2], h[3]);
  }
  *(float4*)(hx + (size_t)b * 4)  = make_float4(h[0], h[1], h[2], h[3]);
  *(float4*)(cxp + (size_t)b * 4) = make_float4(c[0], c[1], c[2], c[3]);
}

// ---------------------------------------------------------------------------
// Fallback (only if workspace can't hold Z): fused, slow but correct.
// ---------------------------------------------------------------------------
__global__ __launch_bounds__(256) void qlstm_fused(
    const float* __restrict__ x,
    const float* __restrict__ Wf, const float* __restrict__ bf,
    const float* __restrict__ Wi, const float* __restrict__ bi,
    const float* __restrict__ Wu, const float* __restrict__ bu,
    const float* __restrict__ Wo, const float* __restrict__ bo,
    const float* __restrict__ thf, const float* __restrict__ thi,
    const float* __restrict__ thu, const float* __restrict__ tho,
    float* __restrict__ out, int T, int B, int D)
{
  int b = blockIdx.x * 256 + threadIdx.x;
  if (b >= B) return;
  GK K;
  load_gk(K, Wf, Wi, Wu, Wo, thf, thi, thu, tho, D);
  const float* Ws[4] = {Wf, Wi, Wu, Wo};
  const float* bs[4] = {bf, bi, bu, bo};
  const float* ts[4] = {thf, thi, thu, tho};
  const int ldw = D + 4;

  float base[12];
#pragma unroll
  for (int g = 0; g < 4; ++g) {
    base[g * 3 + 0] = bs[g][0] + ts[g][0];
    base[g * 3 + 1] = bs[g][1];
    base[g * 3 + 2] = bs[g][3] + ts[g][3];
  }

  float h[4] = {0.f, 0.f, 0.f, 0.f};
  float c[4] = {0.f, 0.f, 0.f, 0.f};
  float* hx  = out + (size_t)T * B * 4;
  float* cxp = hx + (size_t)B * 4;

  for (int t = 0; t < T; ++t) {
    float a[12];
#pragma unroll
    for (int j = 0; j < 12; ++j) a[j] = base[j];
    const float* xp = x + ((size_t)t * B + b) * D;
    for (int k = 0; k < D; k += 4) {
      float4 xv = *(const float4*)(xp + k);
#pragma unroll
      for (int g = 0; g < 4; ++g) {
        const float* W = Ws[g];
#pragma unroll
        for (int jj = 0; jj < 3; ++jj) {
          int row = (jj == 2) ? 3 : jj;
          const float* wp = W + row * ldw + k;
          a[g * 3 + jj] += xv.x * wp[0] + xv.y * wp[1] + xv.z * wp[2] + xv.w * wp[3];
        }
      }
    }
#pragma unroll
    for (int g = 0; g < 4; ++g) {
#pragma unroll
      for (int jj = 0; jj < 3; ++jj) {
        a[g * 3 + jj] += K.wh[g][jj][0] * h[0] + K.wh[g][jj][1] * h[1]
                       + K.wh[g][jj][2] * h[2] + K.wh[g][jj][3] * h[3];
      }
    }
    qlstm_step(a, K, h, c);
    *(float4*)(out + ((size_t)t * B + b) * 4) = make_float4(h[0], h[1], h[2], h[3]);
  }
  *(float4*)(hx + (size_t)b * 4)  = make_float4(h[0], h[1], h[2], h[3]);
  *(float4*)(cxp + (size_t)b * 4) = make_float4(c[0], c[1], c[2], c[3]);
}

// ---------------------------------------------------------------------------
extern "C" void kernel_launch(void* const* d_in, const int* in_sizes, int n_in,
                              void* d_out, int out_size, void* d_ws, size_t ws_size,
                              hipStream_t stream)
{
  const float* x   = (const float*)d_in[0];
  const float* Wf  = (const float*)d_in[1];
  const float* bf  = (const float*)d_in[2];
  const float* Wi  = (const float*)d_in[3];
  const float* bi  = (const float*)d_in[4];
  const float* Wu  = (const float*)d_in[5];
  const float* bu  = (const float*)d_in[6];
  const float* Wo  = (const float*)d_in[7];
  const float* bo  = (const float*)d_in[8];
  const float* thf = (const float*)d_in[9];
  const float* thi = (const float*)d_in[10];
  const float* thu = (const float*)d_in[11];
  const float* tho = (const float*)d_in[12];

  int DH = in_sizes[1] / 4;                 // D + H (H = 4)
  int D  = DH - 4;                          // 128
  long long TB = (long long)in_sizes[0] / D;          // T*B
  int B = (int)(((long long)out_size - 4 * TB) / 8);  // out = 4*T*B + 8*B
  int T = (int)(TB / B);

  size_t zbytes = (size_t)TB * 12 * sizeof(float);
  if (ws_size >= zbytes && (D & 31) == 0) {
    float* Z = (float*)d_ws;
    int gblocks = (int)((TB + 255) / 256);
    qlstm_gemm<<<gblocks, 256, 0, stream>>>(x, Wf, bf, Wi, bi, Wu, bu, Wo, bo,
                                            thf, thi, thu, tho, Z, TB, B, D);
    qlstm_scan<<<(B + 63) / 64, 64, 0, stream>>>(Z, Wf, Wi, Wu, Wo,
                                                 thf, thi, thu, tho,
                                                 (float*)d_out, T, B, D);
  } else {
    qlstm_fused<<<(B + 255) / 256, 256, 0, stream>>>(x, Wf, bf, Wi, bi, Wu, bu, Wo, bo,
                                                     thf, thi, thu, tho,
                                                     (float*)d_out, T, B, D);
  }
}